// Round 7
// baseline (333.745 us; speedup 1.0000x reference)
//
#include <hip/hip_runtime.h>
#include <hip/hip_bf16.h>
#include <math.h>

typedef unsigned int uint;
typedef unsigned short ushort;
typedef __attribute__((ext_vector_type(4))) int i32x4;

#define K_DIM 8192
#define ROW8 8192   // bytes per row of XT8 / YT8 (i8, PLAIN row-major now)
#define N_TILE 78   // 32 XY + 36 XX-tri + 10 YY-tri (256x256 tiles)
#define S_SPLIT 6
#define NKT 64      // K-tiles of BK=128

// ws layout (bytes):
//   0        : double sums[4]           (xy, xx, yy)
//   64       : uint   amax[2]           (absmax bits of x, y)
//   256      : float  csx[2048]
//   8448     : float  csy[1024]
//   16384    : char   XT8[2048][8192]   centered x^T, i8, PLAIN (16 MB)
//   16793600 : char   YT8[1024][8192]   centered y^T, i8, PLAIN (8 MB)
//   25182208 : float  C[78][65536]      partial-C accumulators (19.5 MB)
// total = 44693632 B.
//
// Swizzle now lives in gemm staging SOURCE address: LDS slot u of row r gets
// global unit u ^ (r&7); ds_read XORs identically (LDS content byte-identical
// to R6's proven conflict-free layout).

__device__ __forceinline__ void async16(const void* g, void* l) {
  __builtin_amdgcn_global_load_lds(
      (const __attribute__((address_space(1))) unsigned int*)g,
      (__attribute__((address_space(3))) unsigned int*)l, 16, 0, 0);
}

__device__ __forceinline__ float mk_scale(uint bits) {
  return 127.0f / (__uint_as_float(bits) + 0.06f);
}

__global__ __launch_bounds__(256) void zero_k(double* sums, uint* amax,
                                              float* csx, float* csy) {
  int t = threadIdx.x;
  if (t < 4) sums[t] = 0.0;
  if (t < 2) amax[t] = 0u;
  for (int i = t; i < 2048; i += 256) csx[i] = 0.f;
  for (int i = t; i < 1024; i += 256) csy[i] = 0.f;
}

__global__ __launch_bounds__(256) void zeroC_k(float* C) {
  size_t base = ((size_t)blockIdx.x * 256 + threadIdx.x) * 16;
  float4 z = make_float4(0.f, 0.f, 0.f, 0.f);
#pragma unroll
  for (int j = 0; j < 4; j++) *(float4*)(C + base + j * 4) = z;
}

// 384 blocks: 0..255 -> x (8 colblk x 32 rowblk), 256..383 -> y (4 x 32).
// 256 rows per block: 2x the wave-parallelism of R6's version.
__global__ __launch_bounds__(256) void colsum_k(const float* __restrict__ x,
                                                const float* __restrict__ y,
                                                float* csx, float* csy,
                                                uint* amax) {
  __shared__ float am4[4];
  int bid = blockIdx.x, t = threadIdx.x;
  const float* src; float* dst; uint* adst; int C, cb, rb;
  if (bid < 256) { src = x; dst = csx; adst = amax + 0; C = 2048; cb = bid & 7; rb = bid >> 3; }
  else { int b = bid - 256; src = y; dst = csy; adst = amax + 1; C = 1024; cb = b & 3; rb = b >> 2; }
  int col = cb * 256 + t;
  size_t base = (size_t)(rb * 256) * (size_t)C + (size_t)col;
  float s = 0.f, am = 0.f;
  for (int r = 0; r < 256; r++) {
    float v = src[base + (size_t)r * C];
    s += v;
    am = fmaxf(am, fabsf(v));
  }
  atomicAdd(&dst[col], s);
  for (int off = 32; off; off >>= 1) am = fmaxf(am, __shfl_down(am, off, 64));
  if ((t & 63) == 0) am4[t >> 6] = am;
  __syncthreads();
  if (t == 0) {
    am = fmaxf(fmaxf(am4[0], am4[1]), fmaxf(am4[2], am4[3]));
    atomicMax(adst, __float_as_uint(am));
  }
}

// Center + transpose + i8-quantize. 64m x 128k tiles, PLAIN row-major output
// (full 128-B contiguous stores per row-chunk).
// blocks 0..2047 -> x (mt=bid>>6 in 0..31, kt=bid&63), 2048..3071 -> y.
__global__ __launch_bounds__(256) void centerT_k(const float* __restrict__ x,
                                                 const float* __restrict__ y,
                                                 const float* __restrict__ csx,
                                                 const float* __restrict__ csy,
                                                 const uint* __restrict__ amax,
                                                 char* XT8, char* YT8) {
  __shared__ float tile[64][129];
  int bid = blockIdx.x, t = threadIdx.x;
  const float* src; const float* cs; char* dst; int C, mt, kt; float sc;
  if (bid < 2048) { src = x; cs = csx; dst = XT8; C = 2048; mt = bid >> 6; kt = bid & 63; sc = mk_scale(amax[0]); }
  else { int b = bid - 2048; src = y; cs = csy; dst = YT8; C = 1024; mt = b >> 6; kt = b & 63; sc = mk_scale(amax[1]); }
  int m0 = mt * 64, k0 = kt * 128;

#pragma unroll
  for (int rep = 0; rep < 32; rep++) {
    int idx = rep * 256 + t;
    int kr = idx >> 6, mc = idx & 63;
    tile[mc][kr] = src[(size_t)(k0 + kr) * C + (size_t)(m0 + mc)];
  }
  __syncthreads();

  const float inv_n = 1.0f / 8192.0f;
  int u3 = t & 7, mlb = t >> 3;  // 16B k-unit / m base (0..31)
#pragma unroll
  for (int rep2 = 0; rep2 < 2; rep2++) {
    int ml = mlb + rep2 * 32;
    int m = m0 + ml;
    float mean = cs[m] * inv_n;
    uint wd[4];
#pragma unroll
    for (int jw = 0; jw < 4; jw++) {
      uint wv = 0;
#pragma unroll
      for (int b = 0; b < 4; b++) {
        float f = (tile[ml][u3 * 16 + jw * 4 + b] - mean) * sc;
        int qv = __float2int_rn(f);
        qv = max(-127, min(127, qv));
        wv |= ((uint)(qv & 0xFF)) << (8 * b);
      }
      wd[jw] = wv;
    }
    size_t off = (size_t)m * ROW8 + (size_t)k0 + (size_t)(u3 * 16);
    uint4 v; v.x = wd[0]; v.y = wd[1]; v.z = wd[2]; v.w = wd[3];
    *(uint4*)(dst + off) = v;
  }
}

// tile in [0,78): <32 XY ; <68 XX-tri ; else YY-tri.
__device__ __forceinline__ void tile_decomp(int tile, int* m0, int* n0,
                                            int* which, int* diag) {
  if (tile < 32) { *m0 = (tile >> 2) * 256; *n0 = (tile & 3) * 256; *which = 0; *diag = 0; }
  else if (tile < 68) {
    int idx = tile - 32, ti = 0;
    while (idx >= 8 - ti) { idx -= 8 - ti; ti++; }
    *m0 = ti * 256; *n0 = (ti + idx) * 256; *which = 1; *diag = (idx == 0);
  } else {
    int idx = tile - 68, ti = 0;
    while (idx >= 4 - ti) { idx -= 4 - ti; ti++; }
    *m0 = ti * 256; *n0 = (ti + idx) * 256; *which = 2; *diag = (idx == 0);
  }
}

// i8 K-split GEMM: 78 tiles x 6 K-chunks = 468 blocks x 512 threads (8 waves).
// Tile 256x256, BK=128, SINGLE-buffered 64 KB LDS -> 2 blocks/CU; co-resident
// blocks hide each other's stage drains (m97/m114 regime).
// Swizzle applied on staging SOURCE; ds_read XOR identical to R6 (conflict-free).
__global__ __launch_bounds__(512, 4) void gemm_i8_k(const char* __restrict__ XT8,
                                                    const char* __restrict__ YT8,
                                                    const uint* __restrict__ amax,
                                                    float* __restrict__ Cbuf) {
  __shared__ char lds[65536];  // A 32K | B 32K (single buffer)

  // T1: bijective chunked XCD swizzle over nwg=468 (q=58, r=4), tile-major
  int orig = blockIdx.x;
  int xcd = orig & 7, idx8 = orig >> 3;
  const int q = 468 / 8, r = 468 % 8;
  int off = (xcd < r) ? xcd * (q + 1) : r * (q + 1) + (xcd - r) * q;
  int wgid = off + idx8;
  int s = wgid / N_TILE, tile = wgid - s * N_TILE;

  int m0, n0, which, diag;
  tile_decomp(tile, &m0, &n0, &which, &diag);
  const char* Ab = (which == 2) ? YT8 : XT8;
  const char* Bb = (which == 0) ? YT8 : (which == 1) ? XT8 : YT8;
  const char* Ag = Ab + (size_t)m0 * ROW8;
  const char* Bg = Bb + (size_t)n0 * ROW8;
  float sA = mk_scale(amax[(which == 2) ? 1 : 0]);
  float sB = mk_scale(amax[(which == 0) ? 1 : (which == 1) ? 0 : 1]);
  float invs = 1.0f / (sA * sB);

  int k0t = (NKT * s) / S_SPLIT;        // 0,10,21,32,42,53
  int k1t = (NKT * (s + 1)) / S_SPLIT;  // 10,21,32,42,53,64
  int nst = k1t - k0t;

  int t = threadIdx.x;
  int u = t & 7;          // LDS 16B slot within a row's 128B chunk
  int rr = t >> 3;        // staging row 0..63 (+c*64)
  int w = t >> 6;
  int lane = t & 63;
  int wm = (w >> 2) * 128, wn = (w & 3) * 64;  // 2x4 wave grid
  int lr = lane & 15, lk = lane >> 4;
  const bool doB = !diag;

  i32x4 acc[8][4];
#pragma unroll
  for (int i = 0; i < 8; i++)
#pragma unroll
    for (int j = 0; j < 4; j++)
      acc[i][j] = (i32x4){0, 0, 0, 0};

  // Source-side swizzle: LDS slot u of row gets global unit u ^ (row&7)
#define STAGE(kt)                                                                   \
  {                                                                                 \
    size_t koff = (size_t)(kt) * 128;                                               \
    _Pragma("unroll")                                                               \
    for (int c = 0; c < 4; c++) {                                                   \
      int row = c * 64 + rr;                                                        \
      size_t gsrc = (size_t)row * ROW8 + koff + (size_t)((u ^ (row & 7)) << 4);     \
      async16(Ag + gsrc, lds + row * 128 + u * 16);                                 \
      if (doB)                                                                      \
        async16(Bg + gsrc, lds + 32768 + row * 128 + u * 16);                       \
    }                                                                               \
  }

  for (int i = 0; i < nst; ++i) {
    __syncthreads();  // all waves done reading previous tile
    STAGE(k0t + i);
    __syncthreads();  // drain: buffer staged

    const char* la = lds;
    const char* lb = doB ? (lds + 32768) : lds;
#pragma unroll
    for (int ks = 0; ks < 2; ks++) {
      int ku = ks * 4 + lk;
      i32x4 a[8], b[4];
#pragma unroll
      for (int mi = 0; mi < 8; mi++) {
        int row = wm + mi * 16 + lr;
        a[mi] = *(const i32x4*)(la + row * 128 + ((ku ^ (row & 7)) << 4));
      }
#pragma unroll
      for (int nj = 0; nj < 4; nj++) {
        int row = wn + nj * 16 + lr;
        b[nj] = *(const i32x4*)(lb + row * 128 + ((ku ^ (row & 7)) << 4));
      }
#pragma unroll
      for (int mi = 0; mi < 8; mi++)
#pragma unroll
        for (int nj = 0; nj < 4; nj++)
          acc[mi][nj] = __builtin_amdgcn_mfma_i32_16x16x64_i8(a[mi], b[nj], acc[mi][nj], 0, 0, 0);
    }
  }
#undef STAGE

  // Dequantized partial C. Bijection: w*8192 + frag*256 + e*64 + lane
  // (identical across the 6 K-split siblings -> same slot per logical element).
  float* Ct = Cbuf + (size_t)tile * 65536;
#pragma unroll
  for (int mi = 0; mi < 8; mi++)
#pragma unroll
    for (int nj = 0; nj < 4; nj++)
#pragma unroll
      for (int e = 0; e < 4; e++)
        atomicAdd(&Ct[w * 8192 + (mi * 4 + nj) * 256 + e * 64 + lane],
                  (float)acc[mi][nj][e] * invs);
}

// 78*8 = 624 blocks: square+sum partial C with per-tile weights.
__global__ __launch_bounds__(256) void reduceC_k(const float* __restrict__ C, double* sums) {
  __shared__ double p[4];
  int bid = blockIdx.x, t = threadIdx.x;
  int tile = bid >> 3, seg = bid & 7;
  int m0, n0, which, diag;
  tile_decomp(tile, &m0, &n0, &which, &diag);
  double wgt = diag ? 1.0 : (which == 0 ? 1.0 : 2.0);

  const float* Ct = C + (size_t)tile * 65536 + (size_t)seg * 8192;
  double s = 0.0;
  for (int i = t * 4; i < 8192; i += 1024) {
    float4 v = *(const float4*)(Ct + i);
    s += (double)v.x * v.x + (double)v.y * v.y + (double)v.z * v.z + (double)v.w * v.w;
  }
  for (int off = 32; off; off >>= 1) s += __shfl_down(s, off, 64);
  if ((t & 63) == 0) p[t >> 6] = s;
  __syncthreads();
  if (t == 0) atomicAdd(&sums[which], wgt * (p[0] + p[1] + p[2] + p[3]));
}

__global__ void finalize_k(const double* sums, float* out) {
  double xy = sums[0], xx = sums[1], yy = sums[2];
  out[0] = (float)(xy / (sqrt(xx * yy) + 1e-8));
}

extern "C" void kernel_launch(void* const* d_in, const int* in_sizes, int n_in,
                              void* d_out, int out_size, void* d_ws, size_t ws_size,
                              hipStream_t stream) {
  (void)in_sizes; (void)n_in; (void)out_size; (void)ws_size;
  const float* x = (const float*)d_in[0];
  const float* y = (const float*)d_in[1];
  float* out = (float*)d_out;
  char* ws = (char*)d_ws;
  double* sums = (double*)ws;
  uint* amax = (uint*)(ws + 64);
  float* csx = (float*)(ws + 256);
  float* csy = (float*)(ws + 8448);
  char* XT8 = ws + 16384;
  char* YT8 = ws + 16793600;
  float* Cbuf = (float*)(ws + 25182208);

  zero_k<<<1, 256, 0, stream>>>(sums, amax, csx, csy);
  zeroC_k<<<1248, 256, 0, stream>>>(Cbuf);
  colsum_k<<<384, 256, 0, stream>>>(x, y, csx, csy, amax);
  centerT_k<<<3072, 256, 0, stream>>>(x, y, csx, csy, amax, XT8, YT8);
  gemm_i8_k<<<N_TILE * S_SPLIT, 512, 0, stream>>>(XT8, YT8, amax, Cbuf);
  reduceC_k<<<N_TILE * 8, 256, 0, stream>>>(Cbuf, sums);
  finalize_k<<<1, 1, 0, stream>>>(sums, out);
}

// Round 8
// 115.962 us; speedup vs baseline: 2.8781x; 2.8781x over previous
//
#include <hip/hip_runtime.h>
#include <hip/hip_bf16.h>
#include <math.h>

typedef unsigned int uint;
typedef unsigned short ushort;
typedef __attribute__((ext_vector_type(4))) int i32x4;
typedef __attribute__((ext_vector_type(8))) ushort u16x8;

#define K_DIM 8192
#define ROW8 8192    // bytes per row of XT8 / YT8 (i8, PLAIN row-major)
#define N_TILE 300   // 128 XY (16x8) + 136 XX-tri + 36 YY-tri (128x128 tiles)
#define S_SPLIT 3
#define NKT 64       // K-tiles of BK=128

// ws layout (bytes):
//   0        : double sums[4]           (xy, xx, yy)
//   64       : uint   amax[2]           (absmax bits of x, y)
//   256      : float  csx[2048]
//   8448     : float  csy[1024]
//   16384    : char   XT8[2048][8192]   centered x^T, i8, PLAIN (16 MB)
//   16793600 : char   YT8[1024][8192]   centered y^T, i8, PLAIN (8 MB)
//   25182208 : ushort Cp[900][16384]    sibling-private bf16 partial C (29.5 MB)
// total = 54673408 B  (< 70.8 MB proven available).
//
// GEMM staging swizzle lives in the SOURCE address: LDS slot u of row r gets
// global unit u ^ (r&7); ds_read applies the same XOR (R6/R7-proven, 0 conflicts).

__device__ __forceinline__ void async16(const void* g, void* l) {
  __builtin_amdgcn_global_load_lds(
      (const __attribute__((address_space(1))) unsigned int*)g,
      (__attribute__((address_space(3))) unsigned int*)l, 16, 0, 0);
}

__device__ __forceinline__ ushort f2bf(float f) {
  uint x = __float_as_uint(f);
  uint r = (x + 0x7fffu + ((x >> 16) & 1u)) >> 16;  // RTNE
  return (ushort)r;
}

__device__ __forceinline__ float mk_scale(uint bits) {
  return 127.0f / (__uint_as_float(bits) + 0.06f);
}

__global__ __launch_bounds__(256) void zero_k(double* sums, uint* amax,
                                              float* csx, float* csy) {
  int t = threadIdx.x;
  if (t < 4) sums[t] = 0.0;
  if (t < 2) amax[t] = 0u;
  for (int i = t; i < 2048; i += 256) csx[i] = 0.f;
  for (int i = t; i < 1024; i += 256) csy[i] = 0.f;
}

// 384 blocks: 0..255 -> x (8 colblk x 32 rowblk), 256..383 -> y (4 x 32).
__global__ __launch_bounds__(256) void colsum_k(const float* __restrict__ x,
                                                const float* __restrict__ y,
                                                float* csx, float* csy,
                                                uint* amax) {
  __shared__ float am4[4];
  int bid = blockIdx.x, t = threadIdx.x;
  const float* src; float* dst; uint* adst; int C, cb, rb;
  if (bid < 256) { src = x; dst = csx; adst = amax + 0; C = 2048; cb = bid & 7; rb = bid >> 3; }
  else { int b = bid - 256; src = y; dst = csy; adst = amax + 1; C = 1024; cb = b & 3; rb = b >> 2; }
  int col = cb * 256 + t;
  size_t base = (size_t)(rb * 256) * (size_t)C + (size_t)col;
  float s = 0.f, am = 0.f;
  for (int r = 0; r < 256; r++) {
    float v = src[base + (size_t)r * C];
    s += v;
    am = fmaxf(am, fabsf(v));
  }
  atomicAdd(&dst[col], s);
  for (int off = 32; off; off >>= 1) am = fmaxf(am, __shfl_down(am, off, 64));
  if ((t & 63) == 0) am4[t >> 6] = am;
  __syncthreads();
  if (t == 0) {
    am = fmaxf(fmaxf(am4[0], am4[1]), fmaxf(am4[2], am4[3]));
    atomicMax(adst, __float_as_uint(am));
  }
}

// Center + transpose + i8-quantize. 64m x 128k tiles, PLAIN row-major output.
// blocks 0..2047 -> x (mt=bid>>6 in 0..31, kt=bid&63), 2048..3071 -> y.
__global__ __launch_bounds__(256) void centerT_k(const float* __restrict__ x,
                                                 const float* __restrict__ y,
                                                 const float* __restrict__ csx,
                                                 const float* __restrict__ csy,
                                                 const uint* __restrict__ amax,
                                                 char* XT8, char* YT8) {
  __shared__ float tile[64][129];
  int bid = blockIdx.x, t = threadIdx.x;
  const float* src; const float* cs; char* dst; int C, mt, kt; float sc;
  if (bid < 2048) { src = x; cs = csx; dst = XT8; C = 2048; mt = bid >> 6; kt = bid & 63; sc = mk_scale(amax[0]); }
  else { int b = bid - 2048; src = y; cs = csy; dst = YT8; C = 1024; mt = b >> 6; kt = b & 63; sc = mk_scale(amax[1]); }
  int m0 = mt * 64, k0 = kt * 128;

#pragma unroll
  for (int rep = 0; rep < 32; rep++) {
    int idx = rep * 256 + t;
    int kr = idx >> 6, mc = idx & 63;
    tile[mc][kr] = src[(size_t)(k0 + kr) * C + (size_t)(m0 + mc)];
  }
  __syncthreads();

  const float inv_n = 1.0f / 8192.0f;
  int u3 = t & 7, mlb = t >> 3;
#pragma unroll
  for (int rep2 = 0; rep2 < 2; rep2++) {
    int ml = mlb + rep2 * 32;
    int m = m0 + ml;
    float mean = cs[m] * inv_n;
    uint wd[4];
#pragma unroll
    for (int jw = 0; jw < 4; jw++) {
      uint wv = 0;
#pragma unroll
      for (int b = 0; b < 4; b++) {
        float f = (tile[ml][u3 * 16 + jw * 4 + b] - mean) * sc;
        int qv = __float2int_rn(f);
        qv = max(-127, min(127, qv));
        wv |= ((uint)(qv & 0xFF)) << (8 * b);
      }
      wd[jw] = wv;
    }
    size_t off = (size_t)m * ROW8 + (size_t)k0 + (size_t)(u3 * 16);
    uint4 v; v.x = wd[0]; v.y = wd[1]; v.z = wd[2]; v.w = wd[3];
    *(uint4*)(dst + off) = v;
  }
}

// 128x128-tile decomposition (R1/R2-proven): tile<128 XY ; <264 XX-tri ; else YY-tri.
__device__ __forceinline__ void tile_decomp(int tile, int* m0, int* n0,
                                            int* which, int* diag) {
  if (tile < 128) { *m0 = (tile >> 3) * 128; *n0 = (tile & 7) * 128; *which = 0; *diag = 0; }
  else if (tile < 264) {
    int idx = tile - 128, ti = 0;
    while (idx >= 16 - ti) { idx -= 16 - ti; ti++; }
    *m0 = ti * 128; *n0 = (ti + idx) * 128; *which = 1; *diag = (idx == 0);
  } else {
    int idx = tile - 264, ti = 0;
    while (idx >= 8 - ti) { idx -= 8 - ti; ti++; }
    *m0 = ti * 128; *n0 = (ti + idx) * 128; *which = 2; *diag = (idx == 0);
  }
}

// i8 K-split GEMM: 300 tiles x 3 K-chunks = 900 blocks x 256 threads (4 waves).
// Tile 128x128, BK=128, SINGLE-buffered 32 KB LDS -> ~3.5 blocks/CU (m97 regime:
// co-resident blocks hide each other's stage drains). No atomics: each sibling
// writes its own bf16 partial-C slice.
__global__ __launch_bounds__(256, 4) void gemm_i8_k(const char* __restrict__ XT8,
                                                    const char* __restrict__ YT8,
                                                    const uint* __restrict__ amax,
                                                    ushort* __restrict__ Cp) {
  __shared__ char lds[32768];  // A 16K | B 16K

  // T1: bijective chunked XCD swizzle over nwg=900 (q=112, r=4), tile-major.
  int orig = blockIdx.x;
  int xcd = orig & 7, idx8 = orig >> 3;
  int off = (xcd < 4) ? xcd * 113 : 4 * 113 + (xcd - 4) * 112;
  int wgid = off + idx8;
  int s = wgid / N_TILE, tile = wgid - s * N_TILE;

  int m0, n0, which, diag;
  tile_decomp(tile, &m0, &n0, &which, &diag);
  const char* Ab = (which == 2) ? YT8 : XT8;
  const char* Bb = (which == 0) ? YT8 : (which == 1) ? XT8 : YT8;
  const char* Ag = Ab + (size_t)m0 * ROW8;
  const char* Bg = Bb + (size_t)n0 * ROW8;
  float sA = mk_scale(amax[(which == 2) ? 1 : 0]);
  float sB = mk_scale(amax[(which == 0) ? 1 : (which == 1) ? 0 : 1]);
  float invs = 1.0f / (sA * sB);

  int k0t = (NKT * s) / S_SPLIT;        // 0,21,42
  int k1t = (NKT * (s + 1)) / S_SPLIT;  // 21,42,64
  int nst = k1t - k0t;

  int t = threadIdx.x;
  int u = t & 7;          // LDS 16B slot within a row's 128B chunk
  int rr = t >> 3;        // staging row 0..31 (+c*32)
  int w = t >> 6;
  int lane = t & 63;
  int wm = (w >> 1) * 64, wn = (w & 1) * 64;  // 2x2 wave grid, wave tile 64x64
  int lr = lane & 15, lk = lane >> 4;
  const bool doB = !diag;

  i32x4 acc[4][4];
#pragma unroll
  for (int i = 0; i < 4; i++)
#pragma unroll
    for (int j = 0; j < 4; j++)
      acc[i][j] = (i32x4){0, 0, 0, 0};

  // Source-side swizzle: LDS slot u of row gets global unit u ^ (row&7)
#define STAGE(kt)                                                                   \
  {                                                                                 \
    size_t koff = (size_t)(kt) * 128;                                               \
    _Pragma("unroll")                                                               \
    for (int c = 0; c < 4; c++) {                                                   \
      int row = c * 32 + rr;                                                        \
      size_t gsrc = (size_t)row * ROW8 + koff + (size_t)((u ^ (row & 7)) << 4);     \
      async16(Ag + gsrc, lds + row * 128 + u * 16);                                 \
      if (doB)                                                                      \
        async16(Bg + gsrc, lds + 16384 + row * 128 + u * 16);                       \
    }                                                                               \
  }

  for (int i = 0; i < nst; ++i) {
    __syncthreads();  // all waves done reading previous tile
    STAGE(k0t + i);
    __syncthreads();  // drain: buffer staged

    const char* la = lds;
    const char* lb = doB ? (lds + 16384) : lds;
#pragma unroll
    for (int ks = 0; ks < 2; ks++) {
      int ku = ks * 4 + lk;
      i32x4 a[4], b[4];
#pragma unroll
      for (int mi = 0; mi < 4; mi++) {
        int row = wm + mi * 16 + lr;
        a[mi] = *(const i32x4*)(la + row * 128 + ((ku ^ (row & 7)) << 4));
      }
#pragma unroll
      for (int nj = 0; nj < 4; nj++) {
        int row = wn + nj * 16 + lr;
        b[nj] = *(const i32x4*)(lb + row * 128 + ((ku ^ (row & 7)) << 4));
      }
#pragma unroll
      for (int mi = 0; mi < 4; mi++)
#pragma unroll
        for (int nj = 0; nj < 4; nj++)
          acc[mi][nj] = __builtin_amdgcn_mfma_i32_16x16x64_i8(a[mi], b[nj], acc[mi][nj], 0, 0, 0);
    }
  }
#undef STAGE

  // Sibling-private bf16 partial C (no atomics). Bijection within slice:
  // w*4096 + frag*256 + e*64 + lane  (identical across siblings).
  ushort* Ct = Cp + (size_t)(tile * S_SPLIT + s) * 16384;
#pragma unroll
  for (int mi = 0; mi < 4; mi++)
#pragma unroll
    for (int nj = 0; nj < 4; nj++)
#pragma unroll
      for (int e = 0; e < 4; e++)
        Ct[w * 4096 + (mi * 4 + nj) * 256 + e * 64 + lane] =
            f2bf((float)acc[mi][nj][e] * invs);
}

// 300 blocks: sum 3 bf16 siblings, square, weight, accumulate.
__global__ __launch_bounds__(256) void reduceC_k(const ushort* __restrict__ Cp,
                                                 double* sums) {
  __shared__ double p[4];
  int tile = blockIdx.x, t = threadIdx.x;
  int m0, n0, which, diag;
  tile_decomp(tile, &m0, &n0, &which, &diag);
  double wgt = diag ? 1.0 : (which == 0 ? 1.0 : 2.0);

  const ushort* C0 = Cp + (size_t)(tile * S_SPLIT) * 16384;
  double s = 0.0;
#pragma unroll
  for (int v = 0; v < 8; v++) {
    int idx = t * 64 + v * 8;
    u16x8 a0 = *(const u16x8*)(C0 + idx);
    u16x8 a1 = *(const u16x8*)(C0 + 16384 + idx);
    u16x8 a2 = *(const u16x8*)(C0 + 32768 + idx);
#pragma unroll
    for (int j = 0; j < 8; j++) {
      float c = __uint_as_float((uint)a0[j] << 16) +
                __uint_as_float((uint)a1[j] << 16) +
                __uint_as_float((uint)a2[j] << 16);
      s += (double)(c * c);
    }
  }
  for (int off = 32; off; off >>= 1) s += __shfl_down(s, off, 64);
  if ((t & 63) == 0) p[t >> 6] = s;
  __syncthreads();
  if (t == 0) atomicAdd(&sums[which], wgt * (p[0] + p[1] + p[2] + p[3]));
}

__global__ void finalize_k(const double* sums, float* out) {
  double xy = sums[0], xx = sums[1], yy = sums[2];
  out[0] = (float)(xy / (sqrt(xx * yy) + 1e-8));
}

extern "C" void kernel_launch(void* const* d_in, const int* in_sizes, int n_in,
                              void* d_out, int out_size, void* d_ws, size_t ws_size,
                              hipStream_t stream) {
  (void)in_sizes; (void)n_in; (void)out_size; (void)ws_size;
  const float* x = (const float*)d_in[0];
  const float* y = (const float*)d_in[1];
  float* out = (float*)d_out;
  char* ws = (char*)d_ws;
  double* sums = (double*)ws;
  uint* amax = (uint*)(ws + 64);
  float* csx = (float*)(ws + 256);
  float* csy = (float*)(ws + 8448);
  char* XT8 = ws + 16384;
  char* YT8 = ws + 16793600;
  ushort* Cp = (ushort*)(ws + 25182208);

  zero_k<<<1, 256, 0, stream>>>(sums, amax, csx, csy);
  colsum_k<<<384, 256, 0, stream>>>(x, y, csx, csy, amax);
  centerT_k<<<3072, 256, 0, stream>>>(x, y, csx, csy, amax, XT8, YT8);
  gemm_i8_k<<<N_TILE * S_SPLIT, 256, 0, stream>>>(XT8, YT8, amax, Cp);
  reduceC_k<<<N_TILE, 256, 0, stream>>>(Cp, sums);
  finalize_k<<<1, 1, 0, stream>>>(sums, out);
}